// Round 9
// baseline (33713.565 us; speedup 1.0000x reference)
//
#include <hip/hip_runtime.h>
#include <math.h>

// Problem sizes (fixed by reference)
#define TT 2048
#define IIN 128
#define HHID 512
#define OOUT 64
#define OUT_OFF (64 * HHID)   // h_final [B,H] then outs [B,T,O]

// R9 = R1's exact skeleton (320 thr / 5 waves, 106KB dynamic LDS weights,
// identical relaxed-atomic sync protocol: scalar atomic th loads/stores,
// tid0 poll + barrier, 16-per-group epoch counter) with ONLY the compute
// lane-mapping replaced: R1's W-reads were 8-way bank conflicted (2.36e9
// conflict cycles); new mapping reads W/th as XOR-swizzled ds_read_b128
// (2-way = free, proven in R4-R8 at 6.7e7) and reduces via register
// butterfly (drops the LDS-partials pass + one barrier).
// 16 groups x 16 WGs; group g owns batches 4g..4g+3; WG w owns h-rows
// [32w,32w+32) (waves 0-3, 8 rows each) + Who rows [4w,4w+4) (wave 4).
#define NTHR 320

typedef float f32x4 __attribute__((ext_vector_type(4)));

// float-index swizzle: XOR bits[2:4] with bits[5:7] (within a 512 row)
__device__ __forceinline__ int swzF(int f) {
  return f ^ (((f >> 5) & 7) << 2);
}

// LDS layout (float offsets)
#define LDS_W 0                          // [40][512] rows: 32 Whh + 4 Who + 4 pad
#define LDS_WIH (LDS_W + 40 * 512)       // [32][128] linear
#define LDS_TH (LDS_WIH + 32 * 128)      // [4][512] swizzled
#define LDS_TOTAL (LDS_TH + 4 * 512)     // 26624 floats = 106496 B -> 1 WG/CU

extern "C" __global__ void __launch_bounds__(NTHR, 1)
rnn_kernel(const float* __restrict__ inputs,
           const float* __restrict__ hidden,
           const float* __restrict__ in_noise,
           const float* __restrict__ re_noise,
           const float* __restrict__ Wih,
           const float* __restrict__ Whh,
           const float* __restrict__ bhh,
           const float* __restrict__ Who,
           const float* __restrict__ bho,
           float* __restrict__ out,
           unsigned int* __restrict__ cnt,    // [16] epoch counters, 64-dword stride
           float* __restrict__ th_buf)        // [2][16][4][512] f32
{
  extern __shared__ float smem[];
  const int tid = threadIdx.x;
  const int l  = tid & 63;
  const int wv = tid >> 6;               // wave 0..4 (4 = Who wave)
  const int g = blockIdx.x & 15;         // group
  const int w = blockIdx.x >> 4;         // member 0..15
  const int rsw = ((l >> 2) & 7) << 2;   // read-swizzle XOR term
  const int f0 = (8 * l) ^ rsw;          // swizzled chunk base within a row

  // ---------------- stage weights into LDS (once) ----------------
  for (int c = tid; c < 40 * 128; c += NTHR) {
    int j = c >> 7, k4 = (c & 127) << 2;
    float4 v;
    if (j < 32)      v = *(const float4*)&Whh[(long)(32 * w + j) * HHID + k4];
    else if (j < 36) v = *(const float4*)&Who[(long)(4 * w + (j - 32)) * HHID + k4];
    else             v = make_float4(0.f, 0.f, 0.f, 0.f);
    *(float4*)&smem[LDS_W + j * 512 + swzF(k4)] = v;
  }
  for (int c = tid; c < 32 * 32; c += NTHR) {
    int j = c >> 5, i4 = (c & 31) << 2;
    *(float4*)&smem[LDS_WIH + j * 128 + i4] =
        *(const float4*)&Wih[(long)(32 * w + j) * IIN + i4];
  }

  // ---------------- reduce-output lane mapping (butterfly result) ----------------
  const bool redlane = (l & 1) == 0;     // even lane holds value v = l>>1
  const int v  = (l >> 1) & 31;
  const int rr = v >> 2;                 // local row 0..7 within wave
  const int bb = v & 3;                  // batch
  const int grow = 32 * w + 8 * wv + rr; // global h row (waves 0-3)
  const bool hwave = (wv < 4);

  float bhh_v = 0.f, hreg = 0.f, bho_v = 0.f;
  if (redlane && hwave) {
    bhh_v = bhh[grow];
    hreg = hidden[(long)(4 * g + bb) * HHID + grow];
    __hip_atomic_store(&th_buf[((0 * 16 + g) * 4 + bb) * HHID + grow],
                       tanhf(hreg), __ATOMIC_RELAXED, __HIP_MEMORY_SCOPE_AGENT);
  }
  if (!hwave && redlane && rr < 4) bho_v = bho[4 * w + rr];
  __syncthreads();                       // drains vmcnt; weights staged
  if (tid == 0)
    __hip_atomic_fetch_add(&cnt[g * 64], 1u, __ATOMIC_RELAXED,
                           __HIP_MEMORY_SCOPE_AGENT);

  const unsigned int* cptr = &cnt[g * 64];

  for (int t = 0; t <= TT; ++t) {
    // ---- prefetch x / noise (latency hidden under spin) ----
    float2 xi[4], xn[4];
    float nre = 0.f;
    if (t < TT && hwave) {
      #pragma unroll
      for (int b = 0; b < 4; ++b) {
        long off = ((long)(4 * g + b) * TT + t) * IIN + 2 * l;
        xi[b] = *(const float2*)&inputs[off];
        xn[b] = *(const float2*)&in_noise[off];
      }
      if (redlane)
        nre = re_noise[((long)(4 * g + bb) * TT + t) * HHID + grow];
    }

    // ---- spin: tid0 polls group epoch, barrier releases WG (R1 idiom) ----
    if (tid == 0) {
      const unsigned tgt = 16u * (unsigned)(t + 1);
      while (__hip_atomic_load(cptr, __ATOMIC_RELAXED,
                               __HIP_MEMORY_SCOPE_AGENT) < tgt) { }
    }
    __syncthreads();

    // ---- stage th(t): 6+1 scalar atomic loads per thread (R1 idiom) ----
    const float* thsrc = th_buf + ((long)(t & 1) * 16 + g) * 4 * HHID;
    float vv[6], vt = 0.f;
    #pragma unroll
    for (int it = 0; it < 6; ++it)
      vv[it] = __hip_atomic_load(&thsrc[tid + it * NTHR], __ATOMIC_RELAXED,
                                 __HIP_MEMORY_SCOPE_AGENT);
    if (tid < 128)
      vt = __hip_atomic_load(&thsrc[1920 + tid], __ATOMIC_RELAXED,
                             __HIP_MEMORY_SCOPE_AGENT);

    // ---- Wih @ x (overlaps th load latency) ----
    float accH[32];
    if (t < TT && hwave) {
      float xv[4][2];
      #pragma unroll
      for (int b = 0; b < 4; ++b) {
        xv[b][0] = xi[b].x * (1.f + 0.01f * xn[b].x);
        xv[b][1] = xi[b].y * (1.f + 0.01f * xn[b].y);
      }
      #pragma unroll
      for (int r = 0; r < 8; ++r) {
        float2 wihv = *(const float2*)&smem[LDS_WIH + (8 * wv + r) * 128 + 2 * l];
        #pragma unroll
        for (int b = 0; b < 4; ++b)
          accH[r * 4 + b] = wihv.x * xv[b][0] + wihv.y * xv[b][1];
      }
    } else {
      #pragma unroll
      for (int i = 0; i < 32; ++i) accH[i] = 0.f;
    }

    // ---- write staged th into swizzled LDS tile [4][512] ----
    #pragma unroll
    for (int it = 0; it < 6; ++it) {
      int e = tid + it * NTHR, b = e >> 9, k = e & 511;
      smem[LDS_TH + b * 512 + swzF(k)] = vv[it];
    }
    if (tid < 128) {
      int e = 1920 + tid, b = e >> 9, k = e & 511;
      smem[LDS_TH + b * 512 + swzF(k)] = vt;
    }
    __syncthreads();

    // ---- th chunk into registers (b128, 2-way = free) ----
    f32x4 tha[4], thb[4];
    #pragma unroll
    for (int b = 0; b < 4; ++b) {
      tha[b] = *(const f32x4*)&smem[LDS_TH + b * 512 + f0];
      thb[b] = *(const f32x4*)&smem[LDS_TH + b * 512 + (f0 ^ 4)];
    }

    // ---- W rows @ th : 8 rows/wave (wave 4 = Who rows) ----
    #pragma unroll
    for (int r = 0; r < 8; ++r) {
      int base = LDS_W + (8 * wv + r) * 512;
      f32x4 w0 = *(const f32x4*)&smem[base + f0];
      f32x4 w1 = *(const f32x4*)&smem[base + (f0 ^ 4)];
      #pragma unroll
      for (int b = 0; b < 4; ++b)
        accH[r * 4 + b] += w0.x * tha[b].x + w0.y * tha[b].y +
                           w0.z * tha[b].z + w0.w * tha[b].w +
                           w1.x * thb[b].x + w1.y * thb[b].y +
                           w1.z * thb[b].z + w1.w * thb[b].w;
    }

    // ---- butterfly reduce: even lane l ends with value v=l>>1 ----
    #pragma unroll
    for (int rd = 0; rd < 5; ++rd) {
      const int m = 32 >> rd;
      const int half = 16 >> rd;
      const bool hi = (l & m) != 0;
      #pragma unroll
      for (int j = 0; j < half; ++j) {
        float send = hi ? accH[j] : accH[j + half];
        float recv = __shfl_xor(send, m, 64);
        accH[j] = (hi ? accH[j + half] : accH[j]) + recv;
      }
    }
    accH[0] += __shfl_xor(accH[0], 1, 64);

    // ---- h update + publish th(t+1) (waves 0-3) / out store (wave 4) ----
    if (hwave) {
      if (t < TT && redlane) {
        float dh = -hreg + accH[0] + bhh_v + 0.01f * nre;
        hreg += 0.1f * dh;   // ALPHA = DT/TAU
        __hip_atomic_store(
            &th_buf[((((t + 1) & 1) * 16 + g) * 4 + bb) * HHID + grow],
            tanhf(hreg), __ATOMIC_RELAXED, __HIP_MEMORY_SCOPE_AGENT);
      }
    } else if (t > 0 && redlane && rr < 4) {
      long oof = (long)OUT_OFF + ((long)(4 * g + bb) * TT + (t - 1)) * OOUT
                 + 4 * w + rr;
      out[oof] = accH[0] + bho_v;
    }
    __syncthreads();                     // drains publish/out stores
    if (tid == 0 && t < TT)
      __hip_atomic_fetch_add(&cnt[g * 64], 1u, __ATOMIC_RELAXED,
                             __HIP_MEMORY_SCOPE_AGENT);
  }

  // ---- final hidden state ----
  if (redlane && hwave)
    out[(long)(4 * g + bb) * HHID + grow] = hreg;
}

extern "C" void kernel_launch(void* const* d_in, const int* in_sizes, int n_in,
                              void* d_out, int out_size, void* d_ws, size_t ws_size,
                              hipStream_t stream) {
  const float* inputs  = (const float*)d_in[0];
  const float* hidden  = (const float*)d_in[1];
  const float* innoise = (const float*)d_in[2];
  const float* renoise = (const float*)d_in[3];
  const float* Wih     = (const float*)d_in[4];
  const float* Whh     = (const float*)d_in[5];
  const float* bhh     = (const float*)d_in[6];
  const float* Who     = (const float*)d_in[7];
  const float* bho     = (const float*)d_in[8];
  float* out = (float*)d_out;

  unsigned int* cnt = (unsigned int*)d_ws;              // [16] epochs, 256B stride
  float* th_buf = (float*)((char*)d_ws + 4096);         // [2][16][4][512] f32

  hipMemsetAsync(d_ws, 0, 4096, stream);                // reset epochs

  int lds_bytes = LDS_TOTAL * 4;
  hipFuncSetAttribute(reinterpret_cast<const void*>(rnn_kernel),
                      hipFuncAttributeMaxDynamicSharedMemorySize, lds_bytes);
  hipLaunchKernelGGL(rnn_kernel, dim3(256), dim3(NTHR), lds_bytes, stream,
                     inputs, hidden, innoise, renoise, Wih, Whh, bhh, Who, bho,
                     out, cnt, th_buf);
}